// Round 9
// baseline (184.737 us; speedup 1.0000x reference)
//
#include <hip/hip_runtime.h>

#define DIM 256
#define NHEADS 8
#define HDIM 32

typedef _Float16 half8_t __attribute__((ext_vector_type(8)));
typedef _Float16 half4_t __attribute__((ext_vector_type(4)));
typedef float float4_t __attribute__((ext_vector_type(4)));

__device__ __forceinline__ void gload_lds16(const void* g, void* l) {
    __builtin_amdgcn_global_load_lds((const __attribute__((address_space(1))) void*)g,
                                     (__attribute__((address_space(3))) void*)l,
                                     16, 0, 0);
}

// scale * log2(e): S*scale in exp == exp2(S') with Q pre-scaled by this.
#define QSCALE 0.25503093964976485f

// ---------------------------------------------------------------------------
// prep_w: Wqkv [256,768] -> WqT [768,256] fp16; Wout [256,256] -> WoT fp16.
// 256 blocks.
// ---------------------------------------------------------------------------
__global__ __launch_bounds__(256) void prep_w(const float* __restrict__ Wqkv,
                                              const float* __restrict__ Wout,
                                              _Float16* __restrict__ WqT,
                                              _Float16* __restrict__ WoT) {
    __shared__ float ts[32][33];
    const int bid = blockIdx.x, t = threadIdx.x;
    const float* src; _Float16* dst; int N, kb, nb;
    if (bid < 192) { src = Wqkv; dst = WqT; N = 768; nb = bid % 24; kb = bid / 24; }
    else           { int b3 = bid - 192; src = Wout; dst = WoT; N = 256; nb = b3 % 8; kb = b3 / 8; }
    const int tx = t & 31, ty = t >> 5;
    #pragma unroll
    for (int i = 0; i < 4; ++i)
        ts[ty + i * 8][tx] = src[(size_t)(kb * 32 + ty + i * 8) * N + nb * 32 + tx];
    __syncthreads();
    #pragma unroll
    for (int i = 0; i < 4; ++i) {
        int nl = ty + i * 8;
        dst[(size_t)(nb * 32 + nl) * 256 + kb * 32 + tx] = (_Float16)ts[tx][nl];
    }
}

// ---------------------------------------------------------------------------
// qkv GEMM: C = x[8192,256](fp32, cvt in staging) @ WqT[768,256]^T.
// 64x128 tile, BK=32, 4 waves (32x64). A staged via VALU (fp32->fp16 cvt),
// B staged via global_load_lds. Epilogue routes by n-range:
//   n<256   -> Q : qh[row][col] fp16, PRE-SCALED by QSCALE (for exp2)
//   256-511 -> K : kpack[bh][key][hd]          (1KB contiguous per 16-key frag)
//   512-767 -> V : vp[bh][key/32][hd][key%32]  (1KB contiguous per PV frag)
// ---------------------------------------------------------------------------
__global__ __launch_bounds__(256) void gemm_qkv(const float* __restrict__ x,
                                                const _Float16* __restrict__ BT,
                                                _Float16* __restrict__ qh,
                                                _Float16* __restrict__ kpack,
                                                _Float16* __restrict__ vp) {
    __shared__ alignas(16) _Float16 As[64 * 32];
    __shared__ alignas(16) _Float16 Bs[128 * 32];
    const int t = threadIdx.x, lane = t & 63, wave = t >> 6;
    const int l16 = lane & 15, quad = lane >> 4;
    const int m0 = blockIdx.y * 64, n0 = blockIdx.x * 128;
    const int wr = (wave >> 1) * 32, wc = (wave & 1) * 64;
    const int K = 256;

    float4_t acc[2][4];
    #pragma unroll
    for (int i = 0; i < 2; ++i)
        #pragma unroll
        for (int j = 0; j < 4; ++j) acc[i][j] = (float4_t){0.f, 0.f, 0.f, 0.f};

    const int arow = t >> 2;           // 0..63
    const int acol = (t & 3) * 8;      // halves
    const int srow = lane >> 2;        // 0..15
    const int scol = (lane & 3) * 8;

    for (int k0 = 0; k0 < K; k0 += 32) {
        // A: fp32 load + cvt + LDS write (64 rows x 32 k)
        {
            const float* xp = x + (size_t)(m0 + arow) * K + k0 + acol;
            float tmp[8];
            *reinterpret_cast<float4*>(tmp)     = *reinterpret_cast<const float4*>(xp);
            *reinterpret_cast<float4*>(tmp + 4) = *reinterpret_cast<const float4*>(xp + 4);
            half8_t h;
            #pragma unroll
            for (int j = 0; j < 8; ++j) h[j] = (_Float16)tmp[j];
            *reinterpret_cast<half8_t*>(As + arow * 32 + acol) = h;
        }
        // B: DMA 8 chunks of 16 rows
        gload_lds16(BT + (size_t)(n0 + wave * 16 + srow) * K + k0 + scol, Bs + wave * 512);
        gload_lds16(BT + (size_t)(n0 + 64 + wave * 16 + srow) * K + k0 + scol, Bs + 2048 + wave * 512);
        __syncthreads();
        half8_t af[2], bf[4];
        #pragma unroll
        for (int i = 0; i < 2; ++i)
            af[i] = *reinterpret_cast<const half8_t*>(As + (wr + i * 16 + l16) * 32 + quad * 8);
        #pragma unroll
        for (int j = 0; j < 4; ++j)
            bf[j] = *reinterpret_cast<const half8_t*>(Bs + (wc + j * 16 + l16) * 32 + quad * 8);
        #pragma unroll
        for (int i = 0; i < 2; ++i)
            #pragma unroll
            for (int j = 0; j < 4; ++j)
                acc[i][j] = __builtin_amdgcn_mfma_f32_16x16x32_f16(af[i], bf[j], acc[i][j], 0, 0, 0);
        __syncthreads();
    }

    const int bb = m0 >> 11;
    if (n0 < 256) {
        // Q: row-major, pre-scaled for exp2
        #pragma unroll
        for (int i = 0; i < 2; ++i)
            #pragma unroll
            for (int r = 0; r < 4; ++r) {
                int row = m0 + wr + i * 16 + quad * 4 + r;
                #pragma unroll
                for (int j = 0; j < 4; ++j)
                    qh[(size_t)row * 256 + n0 + wc + j * 16 + l16] =
                        (_Float16)(acc[i][j][r] * QSCALE);
            }
    } else if (n0 < 512) {
        // K: kpack[bh][tok][d]
        #pragma unroll
        for (int i = 0; i < 2; ++i)
            #pragma unroll
            for (int r = 0; r < 4; ++r) {
                int tok = (m0 & 2047) + wr + i * 16 + quad * 4 + r;
                #pragma unroll
                for (int j = 0; j < 4; ++j) {
                    int kc = n0 + wc + j * 16 + l16 - 256;
                    int hh = kc >> 5, dd = kc & 31;
                    kpack[((size_t)(bb * NHEADS + hh) * 2048 + tok) * 32 + dd] =
                        (_Float16)acc[i][j][r];
                }
            }
    } else {
        // V: vp[bh][tok/32][d][tok%32], 4 tokens per half4 store
        #pragma unroll
        for (int i = 0; i < 2; ++i) {
            int tok0 = (m0 & 2047) + wr + i * 16 + quad * 4;
            int chunk = tok0 >> 5, tl = tok0 & 31;
            #pragma unroll
            for (int j = 0; j < 4; ++j) {
                int vc = n0 + wc + j * 16 + l16 - 512;
                int hh = vc >> 5, dd = vc & 31;
                half4_t p;
                #pragma unroll
                for (int r = 0; r < 4; ++r) p[r] = (_Float16)acc[i][j][r];
                *reinterpret_cast<half4_t*>(
                    vp + (((size_t)(bb * NHEADS + hh) * 64 + chunk) * 32 + dd) * 32 + tl) = p;
            }
        }
    }
}

// ---------------------------------------------------------------------------
// MFMA flash attention v8: 64 q/wave, KEY-SPLIT x4 (4 blocks/CU), exp2 with
// pre-scaled Q, denominator via ones-MFMA (no VALU adds, no end shuffles).
// Grid: 1024 = (b,h) x 8 q-blocks(256) x 4 key-quarters(512). Zero barriers.
// S^T = mfma(kf,qf); E -> per-wave es[64][40] (b64 w, b128 r); PV + ones MFMA.
// Partials: NUM[kh] fp16 (unnormalized), DEN[kh] fp32.
// ---------------------------------------------------------------------------
__global__ __launch_bounds__(256, 4) void attn_v8(const _Float16* __restrict__ qh,
                                                  const _Float16* __restrict__ kpack,
                                                  const _Float16* __restrict__ vp,
                                                  _Float16* __restrict__ NUM,
                                                  float* __restrict__ DEN) {
    __shared__ alignas(16) _Float16 es[4][64][40];
    const int bid = blockIdx.x;
    const int kh = bid & 3;
    const int qb = (bid >> 2) & 7;
    const int bh = bid >> 5;
    const int b = bh >> 3, h = bh & 7;
    const int t = threadIdx.x, lane = t & 63, wave = t >> 6;
    const int l16 = lane & 15, quad = lane >> 4;
    const int bN = b * 2048;
    const int q0w = qb * 256 + wave * 64;
    const int kbeg = kh * 512;

    // Q fragments (B-operand of S^T): 4 groups of 16 q (pre-scaled by QSCALE).
    half8_t qf[4];
    {
        const _Float16* qrow = qh + (size_t)(bN + q0w + l16) * 256 + h * HDIM + quad * 8;
        #pragma unroll
        for (int g = 0; g < 4; ++g)
            qf[g] = *reinterpret_cast<const half8_t*>(qrow + (size_t)g * 16 * 256);
    }

    const _Float16* kb_ = kpack + (size_t)bh * 65536;   // [2048][32]
    const _Float16* vb_ = vp + (size_t)bh * 65536;      // [64][32][32]

    float4_t num[4][2], dacc[4];
    #pragma unroll
    for (int g = 0; g < 4; ++g) {
        num[g][0] = (float4_t){0.f, 0.f, 0.f, 0.f};
        num[g][1] = (float4_t){0.f, 0.f, 0.f, 0.f};
        dacc[g]   = (float4_t){0.f, 0.f, 0.f, 0.f};
    }
    half8_t ones;
    #pragma unroll
    for (int j = 0; j < 8; ++j) ones[j] = (_Float16)1.0f;

    _Float16* esw = &es[wave][0][0];
    const float4_t z = {0.f, 0.f, 0.f, 0.f};

    #pragma unroll 2
    for (int k0 = kbeg; k0 < kbeg + 512; k0 += 64) {
        // K frags: 4 x 1KB contiguous; V frags: 2 chunks x 2 hd-halves x 1KB.
        half8_t kf[4], vf[4];
        #pragma unroll
        for (int j = 0; j < 4; ++j)
            kf[j] = *reinterpret_cast<const half8_t*>(
                kb_ + (size_t)(k0 + j * 16 + l16) * 32 + quad * 8);
        const int c0 = k0 >> 5;
        #pragma unroll
        for (int s = 0; s < 2; ++s)
            #pragma unroll
            for (int m = 0; m < 2; ++m)
                vf[s * 2 + m] = *reinterpret_cast<const half8_t*>(
                    vb_ + ((size_t)(c0 + s) * 32 + m * 16 + l16) * 32 + quad * 8);

        // S^T = K Q'^T : lane holds S^T[key=kb*16+quad*4+r][q=g*16+l16]
        float4_t st[4][4];
        #pragma unroll
        for (int kb = 0; kb < 4; ++kb)
            #pragma unroll
            for (int g = 0; g < 4; ++g)
                st[kb][g] = __builtin_amdgcn_mfma_f32_16x16x32_f16(kf[kb], qf[g], z, 0, 0, 0);

        // e = exp2(s') -> fp16 (bare v_exp_f32 + pk-cvt; no muls, no adds)
        half4_t ep[4][4];
        #pragma unroll
        for (int kb = 0; kb < 4; ++kb)
            #pragma unroll
            for (int g = 0; g < 4; ++g)
                #pragma unroll
                for (int r = 0; r < 4; ++r)
                    ep[kb][g][r] = (_Float16)__builtin_exp2f(st[kb][g][r]);

        // Two 32-key chunks: E -> LDS (b64), A-frags back (b128), PV + denom.
        #pragma unroll
        for (int s = 0; s < 2; ++s) {
            #pragma unroll
            for (int tt = 0; tt < 2; ++tt)
                #pragma unroll
                for (int g = 0; g < 4; ++g)
                    *reinterpret_cast<half4_t*>(
                        esw + (g * 16 + l16) * 40 + tt * 16 + quad * 4) = ep[s * 2 + tt][g];

            #pragma unroll
            for (int g = 0; g < 4; ++g) {
                half8_t ef = *reinterpret_cast<const half8_t*>(
                    esw + (g * 16 + l16) * 40 + quad * 8);
                num[g][0] = __builtin_amdgcn_mfma_f32_16x16x32_f16(ef, vf[s * 2],     num[g][0], 0, 0, 0);
                num[g][1] = __builtin_amdgcn_mfma_f32_16x16x32_f16(ef, vf[s * 2 + 1], num[g][1], 0, 0, 0);
                dacc[g]   = __builtin_amdgcn_mfma_f32_16x16x32_f16(ef, ones,          dacc[g],   0, 0, 0);
            }
        }
    }

    // Store partial numerator (fp16) and partial denominator (fp32).
    // num/dacc D-layout: row q = g*16+quad*4+r, col = l16 (dacc cols all equal).
    _Float16* ob = NUM + (size_t)kh * 2097152 + (size_t)(bN + q0w) * DIM + h * HDIM;
    #pragma unroll
    for (int g = 0; g < 4; ++g)
        #pragma unroll
        for (int r = 0; r < 4; ++r) {
            size_t ro = (size_t)(g * 16 + quad * 4 + r) * DIM;
            ob[ro + l16]      = (_Float16)num[g][0][r];
            ob[ro + 16 + l16] = (_Float16)num[g][1][r];
        }
    if (l16 == 0) {
        #pragma unroll
        for (int g = 0; g < 4; ++g)
            #pragma unroll
            for (int r = 0; r < 4; ++r)
                DEN[kh * 65536 + bh * 2048 + q0w + g * 16 + quad * 4 + r] = dacc[g][r];
    }
}

// ---------------------------------------------------------------------------
// gemm2 + combine fused: out = [sum4(NUM)*rcp(sum4(DEN)+eps)] @ WoT^T + bout.
// 64x64 tile, BK=32, 4 waves (32x32). A staged via VALU (combine during
// staging, reciprocals hoisted); B staged via DMA. 512 blocks.
// ---------------------------------------------------------------------------
__global__ __launch_bounds__(256) void gemm2c(const _Float16* __restrict__ NUM,
                                              const float* __restrict__ DEN,
                                              const _Float16* __restrict__ BT,
                                              const float* __restrict__ bias,
                                              float* __restrict__ out) {
    __shared__ alignas(16) _Float16 As[64 * 32];
    __shared__ alignas(16) _Float16 Bs[64 * 32];
    const int t = threadIdx.x, lane = t & 63, wave = t >> 6;
    const int l16 = lane & 15, quad = lane >> 4;
    const int m0 = blockIdx.y * 64, n0 = blockIdx.x * 64;
    const int wr = (wave >> 1) * 32, wc = (wave & 1) * 32;
    const int bb = m0 >> 11;

    const int arow = t >> 2;            // 0..63
    const int acol = (t & 3) * 8;       // halves
    const int myrow = m0 + arow;
    _Float16 rcp8[8];
    #pragma unroll
    for (int hh = 0; hh < 8; ++hh) {
        int di = (bb * 8 + hh) * 2048 + (myrow & 2047);
        float d = DEN[di] + DEN[di + 65536] + DEN[di + 131072] + DEN[di + 196608];
        rcp8[hh] = (_Float16)(1.f / (d + 1e-6f));
    }
    const _Float16* np = NUM + (size_t)myrow * 256 + acol;

    float4_t acc[2][2];
    #pragma unroll
    for (int i = 0; i < 2; ++i)
        #pragma unroll
        for (int j = 0; j < 2; ++j) acc[i][j] = (float4_t){0.f, 0.f, 0.f, 0.f};

    for (int k0 = 0; k0 < 256; k0 += 32) {
        half8_t s0 = *reinterpret_cast<const half8_t*>(np + k0);
        half8_t s1 = *reinterpret_cast<const half8_t*>(np + k0 + 2097152);
        half8_t s2 = *reinterpret_cast<const half8_t*>(np + k0 + 2 * 2097152);
        half8_t s3 = *reinterpret_cast<const half8_t*>(np + k0 + 3 * 2097152);
        *reinterpret_cast<half8_t*>(As + arow * 32 + acol) =
            ((s0 + s1) + (s2 + s3)) * rcp8[k0 >> 5];
        gload_lds16(BT + (size_t)(n0 + arow) * 256 + k0 + acol, Bs + t * 8);
        __syncthreads();
        half8_t af[2], bf[2];
        #pragma unroll
        for (int i = 0; i < 2; ++i)
            af[i] = *reinterpret_cast<const half8_t*>(As + (wr + i * 16 + l16) * 32 + quad * 8);
        #pragma unroll
        for (int j = 0; j < 2; ++j)
            bf[j] = *reinterpret_cast<const half8_t*>(Bs + (wc + j * 16 + l16) * 32 + quad * 8);
        #pragma unroll
        for (int i = 0; i < 2; ++i)
            #pragma unroll
            for (int j = 0; j < 2; ++j)
                acc[i][j] = __builtin_amdgcn_mfma_f32_16x16x32_f16(af[i], bf[j], acc[i][j], 0, 0, 0);
        __syncthreads();
    }

    #pragma unroll
    for (int i = 0; i < 2; ++i)
        #pragma unroll
        for (int r = 0; r < 4; ++r) {
            int row = m0 + wr + i * 16 + quad * 4 + r;
            #pragma unroll
            for (int j = 0; j < 2; ++j) {
                int col = n0 + wc + j * 16 + l16;
                out[(size_t)row * 256 + col] = acc[i][j][r] + bias[col];
            }
        }
}

extern "C" void kernel_launch(void* const* d_in, const int* in_sizes, int n_in,
                              void* d_out, int out_size, void* d_ws, size_t ws_size,
                              hipStream_t stream) {
    const float* x    = (const float*)d_in[0];
    const float* Wqkv = (const float*)d_in[1];
    const float* Wout = (const float*)d_in[2];
    const float* bout = (const float*)d_in[3];
    float* out = (float*)d_out;
    const int M = 8192;

    _Float16* WqT   = (_Float16*)d_ws;                 // [768,256]
    _Float16* WoT   = WqT + 768 * 256;                 // [256,256]
    _Float16* qh    = WoT + 256 * 256;                 // [8192,256] (pre-scaled)
    _Float16* kpack = qh + (size_t)M * DIM;            // [32][2048][32]
    _Float16* vp    = kpack + (size_t)32 * 2048 * 32;  // [32][64][32][32]
    _Float16* NUM   = vp + (size_t)32 * 2048 * 32;     // [4][8192,256]
    float*    DEN   = (float*)(NUM + (size_t)4 * M * DIM);  // [4][65536]

    hipLaunchKernelGGL(prep_w, dim3(256), dim3(256), 0, stream, Wqkv, Wout, WqT, WoT);
    hipLaunchKernelGGL(gemm_qkv, dim3(6, 128), dim3(256), 0, stream, x, WqT, qh, kpack, vp);
    hipLaunchKernelGGL(attn_v8, dim3(1024), dim3(256), 0, stream, qh, kpack, vp, NUM, DEN);
    hipLaunchKernelGGL(gemm2c, dim3(4, 128), dim3(256), 0, stream, NUM, DEN, WoT, bout, out);
}

// Round 10
// 148.541 us; speedup vs baseline: 1.2437x; 1.2437x over previous
//
#include <hip/hip_runtime.h>

#define DIM 256
#define NHEADS 8
#define HDIM 32

typedef _Float16 half8_t __attribute__((ext_vector_type(8)));
typedef _Float16 half4_t __attribute__((ext_vector_type(4)));
typedef float float4_t __attribute__((ext_vector_type(4)));

__device__ __forceinline__ void gload_lds16(const void* g, void* l) {
    __builtin_amdgcn_global_load_lds((const __attribute__((address_space(1))) void*)g,
                                     (__attribute__((address_space(3))) void*)l,
                                     16, 0, 0);
}

// scale * log2(e): exp(S*scale) == exp2(S') with Q pre-scaled by this.
#define QSCALE 0.25503093964976485f

// ---------------------------------------------------------------------------
// prep_w: Wqkv [256,768] -> WqT [768,256] fp16; Wout [256,256] -> WoT fp16.
// ---------------------------------------------------------------------------
__global__ __launch_bounds__(256) void prep_w(const float* __restrict__ Wqkv,
                                              const float* __restrict__ Wout,
                                              _Float16* __restrict__ WqT,
                                              _Float16* __restrict__ WoT) {
    __shared__ float ts[32][33];
    const int bid = blockIdx.x, t = threadIdx.x;
    const float* src; _Float16* dst; int N, kb, nb;
    if (bid < 192) { src = Wqkv; dst = WqT; N = 768; nb = bid % 24; kb = bid / 24; }
    else           { int b3 = bid - 192; src = Wout; dst = WoT; N = 256; nb = b3 % 8; kb = b3 / 8; }
    const int tx = t & 31, ty = t >> 5;
    #pragma unroll
    for (int i = 0; i < 4; ++i)
        ts[ty + i * 8][tx] = src[(size_t)(kb * 32 + ty + i * 8) * N + nb * 32 + tx];
    __syncthreads();
    #pragma unroll
    for (int i = 0; i < 4; ++i) {
        int nl = ty + i * 8;
        dst[(size_t)(nb * 32 + nl) * 256 + kb * 32 + tx] = (_Float16)ts[tx][nl];
    }
}

// ---------------------------------------------------------------------------
// qkv GEMM: C = x[8192,256](fp32, cvt in staging) @ WqT[768,256]^T.
// 64x128 tile, BK=32, 4 waves (32x64). Epilogue routes by n-range:
//   n<256   -> Q : qh[row][col] fp16, PRE-SCALED by QSCALE (for exp2)
//   256-511 -> K : kpack[bh][key][dphys], 8-half blocks XOR-swizzled by
//                  ((key>>1)&3) so attn's LDS b128 reads are 2-way (free)
//   512-767 -> V : vp[bh][key/32][d][tphys], tok blocks swizzled by ((d>>1)&3)
// ---------------------------------------------------------------------------
__global__ __launch_bounds__(256) void gemm_qkv(const float* __restrict__ x,
                                                const _Float16* __restrict__ BT,
                                                _Float16* __restrict__ qh,
                                                _Float16* __restrict__ kpack,
                                                _Float16* __restrict__ vp) {
    __shared__ alignas(16) _Float16 As[64 * 32];
    __shared__ alignas(16) _Float16 Bs[128 * 32];
    const int t = threadIdx.x, lane = t & 63, wave = t >> 6;
    const int l16 = lane & 15, quad = lane >> 4;
    const int m0 = blockIdx.y * 64, n0 = blockIdx.x * 128;
    const int wr = (wave >> 1) * 32, wc = (wave & 1) * 64;
    const int K = 256;

    float4_t acc[2][4];
    #pragma unroll
    for (int i = 0; i < 2; ++i)
        #pragma unroll
        for (int j = 0; j < 4; ++j) acc[i][j] = (float4_t){0.f, 0.f, 0.f, 0.f};

    const int arow = t >> 2;           // 0..63
    const int acol = (t & 3) * 8;      // halves
    const int srow = lane >> 2;        // 0..15
    const int scol = (lane & 3) * 8;

    for (int k0 = 0; k0 < K; k0 += 32) {
        {
            const float* xp = x + (size_t)(m0 + arow) * K + k0 + acol;
            float tmp[8];
            *reinterpret_cast<float4*>(tmp)     = *reinterpret_cast<const float4*>(xp);
            *reinterpret_cast<float4*>(tmp + 4) = *reinterpret_cast<const float4*>(xp + 4);
            half8_t h;
            #pragma unroll
            for (int j = 0; j < 8; ++j) h[j] = (_Float16)tmp[j];
            *reinterpret_cast<half8_t*>(As + arow * 32 + acol) = h;
        }
        gload_lds16(BT + (size_t)(n0 + wave * 16 + srow) * K + k0 + scol, Bs + wave * 512);
        gload_lds16(BT + (size_t)(n0 + 64 + wave * 16 + srow) * K + k0 + scol, Bs + 2048 + wave * 512);
        __syncthreads();
        half8_t af[2], bf[4];
        #pragma unroll
        for (int i = 0; i < 2; ++i)
            af[i] = *reinterpret_cast<const half8_t*>(As + (wr + i * 16 + l16) * 32 + quad * 8);
        #pragma unroll
        for (int j = 0; j < 4; ++j)
            bf[j] = *reinterpret_cast<const half8_t*>(Bs + (wc + j * 16 + l16) * 32 + quad * 8);
        #pragma unroll
        for (int i = 0; i < 2; ++i)
            #pragma unroll
            for (int j = 0; j < 4; ++j)
                acc[i][j] = __builtin_amdgcn_mfma_f32_16x16x32_f16(af[i], bf[j], acc[i][j], 0, 0, 0);
        __syncthreads();
    }

    const int bb = m0 >> 11;
    if (n0 < 256) {
        // Q: row-major, pre-scaled for exp2
        #pragma unroll
        for (int i = 0; i < 2; ++i)
            #pragma unroll
            for (int r = 0; r < 4; ++r) {
                int row = m0 + wr + i * 16 + quad * 4 + r;
                #pragma unroll
                for (int j = 0; j < 4; ++j)
                    qh[(size_t)row * 256 + n0 + wc + j * 16 + l16] =
                        (_Float16)(acc[i][j][r] * QSCALE);
            }
    } else if (n0 < 512) {
        // K: kpack[bh][tok][dphys], 8-half blocks swizzled by ((tok>>1)&3)
        #pragma unroll
        for (int i = 0; i < 2; ++i)
            #pragma unroll
            for (int r = 0; r < 4; ++r) {
                int tok = (m0 & 2047) + wr + i * 16 + quad * 4 + r;
                int sw = (tok >> 1) & 3;
                #pragma unroll
                for (int j = 0; j < 4; ++j) {
                    int kc = n0 + wc + j * 16 + l16 - 256;
                    int hh = kc >> 5, dd = kc & 31;
                    int dph = (((dd >> 3) ^ sw) << 3) | (dd & 7);
                    kpack[((size_t)(bb * NHEADS + hh) * 2048 + tok) * 32 + dph] =
                        (_Float16)acc[i][j][r];
                }
            }
    } else {
        // V: vp[bh][chunk][d][tphys], tok blocks swizzled by ((d>>1)&3)
        #pragma unroll
        for (int i = 0; i < 2; ++i) {
            int tok0 = (m0 & 2047) + wr + i * 16 + quad * 4;
            int chunk = tok0 >> 5, tl = tok0 & 31;
            #pragma unroll
            for (int j = 0; j < 4; ++j) {
                int vc = n0 + wc + j * 16 + l16 - 512;
                int hh = vc >> 5, dd = vc & 31;
                int tph = ((((tl >> 3) ^ ((dd >> 1) & 3)) << 3)) | (tl & 7);
                half4_t p;
                #pragma unroll
                for (int r = 0; r < 4; ++r) p[r] = (_Float16)acc[i][j][r];
                *reinterpret_cast<half4_t*>(
                    vp + (((size_t)(bb * NHEADS + hh) * 64 + chunk) * 32 + dd) * 32 + tph) = p;
            }
        }
    }
}

// ---------------------------------------------------------------------------
// MFMA flash attention v9: kh x4 (4 blocks/CU) + LDS-staged K/V tiles via
// global_load_lds (double-buffered, 1 barrier/iter) — kills the 4x redundant
// per-wave global fragment loads that thrashed L1/L2 in v8. exp2 w/ pre-scaled
// Q; denominator via ones-MFMA. Swizzled K/V layouts -> 2-way LDS reads.
// Grid: 1024 = (b,h) x 8 q-blocks(256) x 4 key-quarters(512).
// ---------------------------------------------------------------------------
__global__ __launch_bounds__(256, 4) void attn_v9(const _Float16* __restrict__ qh,
                                                  const _Float16* __restrict__ kpack,
                                                  const _Float16* __restrict__ vp,
                                                  _Float16* __restrict__ NUM,
                                                  float* __restrict__ DEN) {
    __shared__ alignas(16) _Float16 es[4][64][40];      // 20 KB
    __shared__ alignas(16) _Float16 kt[2][64][32];      // 8 KB  [key][dphys]
    __shared__ alignas(16) _Float16 vt[2][2][32][32];   // 8 KB  [s][d][tphys]
    const int bid = blockIdx.x;
    const int kh = bid & 3;
    const int qb = (bid >> 2) & 7;
    const int bh = bid >> 5;
    const int b = bh >> 3, h = bh & 7;
    const int t = threadIdx.x, lane = t & 63, wave = t >> 6;
    const int l16 = lane & 15, quad = lane >> 4;
    const int bN = b * 2048;
    const int q0w = qb * 256 + wave * 64;
    const int kbeg = kh * 512;

    // Q fragments (B-operand of S^T): 4 groups of 16 q (pre-scaled).
    half8_t qf[4];
    {
        const _Float16* qrow = qh + (size_t)(bN + q0w + l16) * 256 + h * HDIM + quad * 8;
        #pragma unroll
        for (int g = 0; g < 4; ++g)
            qf[g] = *reinterpret_cast<const half8_t*>(qrow + (size_t)g * 16 * 256);
    }

    const _Float16* kb_ = kpack + (size_t)bh * 65536;   // [2048][32] swizzled
    const _Float16* vb_ = vp + (size_t)bh * 65536;      // [64][32][32] swizzled
    const int vs = wave >> 1, vm = wave & 1;            // V staging split

    float4_t num[4][2], dacc[4];
    #pragma unroll
    for (int g = 0; g < 4; ++g) {
        num[g][0] = (float4_t){0.f, 0.f, 0.f, 0.f};
        num[g][1] = (float4_t){0.f, 0.f, 0.f, 0.f};
        dacc[g]   = (float4_t){0.f, 0.f, 0.f, 0.f};
    }
    half8_t ones;
    #pragma unroll
    for (int j = 0; j < 8; ++j) ones[j] = (_Float16)1.0f;

    _Float16* esw = &es[wave][0][0];
    const float4_t z = {0.f, 0.f, 0.f, 0.f};
    const int sw = (l16 >> 1) & 3;                      // read-side swizzle

    // prologue: stage tile 0
    gload_lds16(kb_ + (size_t)(kbeg + wave * 16) * 32 + lane * 8, &kt[0][wave * 16][0]);
    gload_lds16(vb_ + ((size_t)((kbeg >> 5) + vs) * 32 + vm * 16) * 32 + lane * 8,
                &vt[0][vs][vm * 16][0]);
    __syncthreads();

    int p = 0;
    for (int it = 0; it < 8; ++it) {
        const int k0 = kbeg + it * 64;
        if (it < 7) {   // stage next tile into the other buffer
            gload_lds16(kb_ + (size_t)(k0 + 64 + wave * 16) * 32 + lane * 8,
                        &kt[p ^ 1][wave * 16][0]);
            gload_lds16(vb_ + ((size_t)(((k0 + 64) >> 5) + vs) * 32 + vm * 16) * 32 + lane * 8,
                        &vt[p ^ 1][vs][vm * 16][0]);
        }

        // K/V fragments from LDS (swizzled, 2-way conflict = free)
        half8_t kf[4], vf[4];
        #pragma unroll
        for (int j = 0; j < 4; ++j)
            kf[j] = *reinterpret_cast<const half8_t*>(
                &kt[p][j * 16 + l16][(quad ^ sw) * 8]);
        #pragma unroll
        for (int s = 0; s < 2; ++s)
            #pragma unroll
            for (int m = 0; m < 2; ++m)
                vf[s * 2 + m] = *reinterpret_cast<const half8_t*>(
                    &vt[p][s][m * 16 + l16][(quad ^ sw) * 8]);

        // S^T = K Q'^T : lane holds S^T[key=kb*16+quad*4+r][q=g*16+l16]
        float4_t st[4][4];
        #pragma unroll
        for (int kb = 0; kb < 4; ++kb)
            #pragma unroll
            for (int g = 0; g < 4; ++g)
                st[kb][g] = __builtin_amdgcn_mfma_f32_16x16x32_f16(kf[kb], qf[g], z, 0, 0, 0);

        // e = exp2(s') -> fp16
        half4_t ep[4][4];
        #pragma unroll
        for (int kb = 0; kb < 4; ++kb)
            #pragma unroll
            for (int g = 0; g < 4; ++g)
                #pragma unroll
                for (int r = 0; r < 4; ++r)
                    ep[kb][g][r] = (_Float16)__builtin_exp2f(st[kb][g][r]);

        // Two 32-key chunks: E -> LDS (b64), A-frags back (b128), PV + denom.
        #pragma unroll
        for (int s = 0; s < 2; ++s) {
            #pragma unroll
            for (int tt = 0; tt < 2; ++tt)
                #pragma unroll
                for (int g = 0; g < 4; ++g)
                    *reinterpret_cast<half4_t*>(
                        esw + (g * 16 + l16) * 40 + tt * 16 + quad * 4) = ep[s * 2 + tt][g];

            #pragma unroll
            for (int g = 0; g < 4; ++g) {
                half8_t ef = *reinterpret_cast<const half8_t*>(
                    esw + (g * 16 + l16) * 40 + quad * 8);
                num[g][0] = __builtin_amdgcn_mfma_f32_16x16x32_f16(ef, vf[s * 2],     num[g][0], 0, 0, 0);
                num[g][1] = __builtin_amdgcn_mfma_f32_16x16x32_f16(ef, vf[s * 2 + 1], num[g][1], 0, 0, 0);
                dacc[g]   = __builtin_amdgcn_mfma_f32_16x16x32_f16(ef, ones,          dacc[g],   0, 0, 0);
            }
        }
        __syncthreads();   // all waves done with buf p; DMA of p^1 drained
        p ^= 1;
    }

    // Store partial numerator (fp16) and partial denominator (fp32).
    _Float16* ob = NUM + (size_t)kh * 2097152 + (size_t)(bN + q0w) * DIM + h * HDIM;
    #pragma unroll
    for (int g = 0; g < 4; ++g)
        #pragma unroll
        for (int r = 0; r < 4; ++r) {
            size_t ro = (size_t)(g * 16 + quad * 4 + r) * DIM;
            ob[ro + l16]      = (_Float16)num[g][0][r];
            ob[ro + 16 + l16] = (_Float16)num[g][1][r];
        }
    if (l16 == 0) {
        #pragma unroll
        for (int g = 0; g < 4; ++g)
            #pragma unroll
            for (int r = 0; r < 4; ++r)
                DEN[kh * 65536 + bh * 2048 + q0w + g * 16 + quad * 4 + r] = dacc[g][r];
    }
}

// ---------------------------------------------------------------------------
// gemm2 + combine fused: out = [sum4(NUM)*rcp(sum4(DEN)+eps)] @ WoT^T + bout.
// 64x64 tile, BK=32, 4 waves (32x32). 512 blocks.
// ---------------------------------------------------------------------------
__global__ __launch_bounds__(256) void gemm2c(const _Float16* __restrict__ NUM,
                                              const float* __restrict__ DEN,
                                              const _Float16* __restrict__ BT,
                                              const float* __restrict__ bias,
                                              float* __restrict__ out) {
    __shared__ alignas(16) _Float16 As[64 * 32];
    __shared__ alignas(16) _Float16 Bs[64 * 32];
    const int t = threadIdx.x, lane = t & 63, wave = t >> 6;
    const int l16 = lane & 15, quad = lane >> 4;
    const int m0 = blockIdx.y * 64, n0 = blockIdx.x * 64;
    const int wr = (wave >> 1) * 32, wc = (wave & 1) * 32;
    const int bb = m0 >> 11;

    const int arow = t >> 2;            // 0..63
    const int acol = (t & 3) * 8;       // halves
    const int myrow = m0 + arow;
    _Float16 rcp8[8];
    #pragma unroll
    for (int hh = 0; hh < 8; ++hh) {
        int di = (bb * 8 + hh) * 2048 + (myrow & 2047);
        float d = DEN[di] + DEN[di + 65536] + DEN[di + 131072] + DEN[di + 196608];
        rcp8[hh] = (_Float16)(1.f / (d + 1e-6f));
    }
    const _Float16* np = NUM + (size_t)myrow * 256 + acol;

    float4_t acc[2][2];
    #pragma unroll
    for (int i = 0; i < 2; ++i)
        #pragma unroll
        for (int j = 0; j < 2; ++j) acc[i][j] = (float4_t){0.f, 0.f, 0.f, 0.f};

    for (int k0 = 0; k0 < 256; k0 += 32) {
        half8_t s0 = *reinterpret_cast<const half8_t*>(np + k0);
        half8_t s1 = *reinterpret_cast<const half8_t*>(np + k0 + 2097152);
        half8_t s2 = *reinterpret_cast<const half8_t*>(np + k0 + 2 * 2097152);
        half8_t s3 = *reinterpret_cast<const half8_t*>(np + k0 + 3 * 2097152);
        *reinterpret_cast<half8_t*>(As + arow * 32 + acol) =
            ((s0 + s1) + (s2 + s3)) * rcp8[k0 >> 5];
        gload_lds16(BT + (size_t)(n0 + arow) * 256 + k0 + acol, Bs + t * 8);
        __syncthreads();
        half8_t af[2], bf[2];
        #pragma unroll
        for (int i = 0; i < 2; ++i)
            af[i] = *reinterpret_cast<const half8_t*>(As + (wr + i * 16 + l16) * 32 + quad * 8);
        #pragma unroll
        for (int j = 0; j < 2; ++j)
            bf[j] = *reinterpret_cast<const half8_t*>(Bs + (wc + j * 16 + l16) * 32 + quad * 8);
        #pragma unroll
        for (int i = 0; i < 2; ++i)
            #pragma unroll
            for (int j = 0; j < 2; ++j)
                acc[i][j] = __builtin_amdgcn_mfma_f32_16x16x32_f16(af[i], bf[j], acc[i][j], 0, 0, 0);
        __syncthreads();
    }

    #pragma unroll
    for (int i = 0; i < 2; ++i)
        #pragma unroll
        for (int r = 0; r < 4; ++r) {
            int row = m0 + wr + i * 16 + quad * 4 + r;
            #pragma unroll
            for (int j = 0; j < 2; ++j) {
                int col = n0 + wc + j * 16 + l16;
                out[(size_t)row * 256 + col] = acc[i][j][r] + bias[col];
            }
        }
}

extern "C" void kernel_launch(void* const* d_in, const int* in_sizes, int n_in,
                              void* d_out, int out_size, void* d_ws, size_t ws_size,
                              hipStream_t stream) {
    const float* x    = (const float*)d_in[0];
    const float* Wqkv = (const float*)d_in[1];
    const float* Wout = (const float*)d_in[2];
    const float* bout = (const float*)d_in[3];
    float* out = (float*)d_out;
    const int M = 8192;

    _Float16* WqT   = (_Float16*)d_ws;                 // [768,256]
    _Float16* WoT   = WqT + 768 * 256;                 // [256,256]
    _Float16* qh    = WoT + 256 * 256;                 // [8192,256] (pre-scaled)
    _Float16* kpack = qh + (size_t)M * DIM;            // [32][2048][32] swizzled
    _Float16* vp    = kpack + (size_t)32 * 2048 * 32;  // [32][64][32][32] swizzled
    _Float16* NUM   = vp + (size_t)32 * 2048 * 32;     // [4][8192,256]
    float*    DEN   = (float*)(NUM + (size_t)4 * M * DIM);  // [4][65536]

    hipLaunchKernelGGL(prep_w, dim3(256), dim3(256), 0, stream, Wqkv, Wout, WqT, WoT);
    hipLaunchKernelGGL(gemm_qkv, dim3(6, 128), dim3(256), 0, stream, x, WqT, qh, kpack, vp);
    hipLaunchKernelGGL(attn_v9, dim3(1024), dim3(256), 0, stream, qh, kpack, vp, NUM, DEN);
    hipLaunchKernelGGL(gemm2c, dim3(4, 128), dim3(256), 0, stream, NUM, DEN, WoT, bout, out);
}

// Round 11
// 143.522 us; speedup vs baseline: 1.2872x; 1.0350x over previous
//
#include <hip/hip_runtime.h>

#define DIM 256
#define NHEADS 8
#define HDIM 32

typedef _Float16 half8_t __attribute__((ext_vector_type(8)));
typedef _Float16 half4_t __attribute__((ext_vector_type(4)));
typedef float float4_t __attribute__((ext_vector_type(4)));

__device__ __forceinline__ void gload_lds16(const void* g, void* l) {
    __builtin_amdgcn_global_load_lds((const __attribute__((address_space(1))) void*)g,
                                     (__attribute__((address_space(3))) void*)l,
                                     16, 0, 0);
}

// scale * log2(e): exp(S*scale) == exp2(S') with Q pre-scaled by this.
#define QSCALE 0.25503093964976485f

// ---------------------------------------------------------------------------
// prep_w: Wqkv [256,768] -> WqT [768,256] fp16; Wout [256,256] -> WoT fp16.
// ---------------------------------------------------------------------------
__global__ __launch_bounds__(256) void prep_w(const float* __restrict__ Wqkv,
                                              const float* __restrict__ Wout,
                                              _Float16* __restrict__ WqT,
                                              _Float16* __restrict__ WoT) {
    __shared__ float ts[32][33];
    const int bid = blockIdx.x, t = threadIdx.x;
    const float* src; _Float16* dst; int N, kb, nb;
    if (bid < 192) { src = Wqkv; dst = WqT; N = 768; nb = bid % 24; kb = bid / 24; }
    else           { int b3 = bid - 192; src = Wout; dst = WoT; N = 256; nb = b3 % 8; kb = b3 / 8; }
    const int tx = t & 31, ty = t >> 5;
    #pragma unroll
    for (int i = 0; i < 4; ++i)
        ts[ty + i * 8][tx] = src[(size_t)(kb * 32 + ty + i * 8) * N + nb * 32 + tx];
    __syncthreads();
    #pragma unroll
    for (int i = 0; i < 4; ++i) {
        int nl = ty + i * 8;
        dst[(size_t)(nb * 32 + nl) * 256 + kb * 32 + tx] = (_Float16)ts[tx][nl];
    }
}

// ---------------------------------------------------------------------------
// qkv GEMM: C = x[8192,256](fp32, cvt in staging) @ WqT[768,256]^T.
// 64x128 tile, BK=32, 4 waves (32x64). Epilogue routes by n-range:
//   n<256   -> Q : qh[row][col] fp16, PRE-SCALED by QSCALE (for exp2)
//   256-511 -> K : kpack[bh][key][d]           (1KB contiguous per 16-key frag)
//   512-767 -> V : vp[bh][key/32][d][key%32]   (1KB contiguous per PV frag)
// ---------------------------------------------------------------------------
__global__ __launch_bounds__(256) void gemm_qkv(const float* __restrict__ x,
                                                const _Float16* __restrict__ BT,
                                                _Float16* __restrict__ qh,
                                                _Float16* __restrict__ kpack,
                                                _Float16* __restrict__ vp) {
    __shared__ alignas(16) _Float16 As[64 * 32];
    __shared__ alignas(16) _Float16 Bs[128 * 32];
    const int t = threadIdx.x, lane = t & 63, wave = t >> 6;
    const int l16 = lane & 15, quad = lane >> 4;
    const int m0 = blockIdx.y * 64, n0 = blockIdx.x * 128;
    const int wr = (wave >> 1) * 32, wc = (wave & 1) * 64;
    const int K = 256;

    float4_t acc[2][4];
    #pragma unroll
    for (int i = 0; i < 2; ++i)
        #pragma unroll
        for (int j = 0; j < 4; ++j) acc[i][j] = (float4_t){0.f, 0.f, 0.f, 0.f};

    const int arow = t >> 2;           // 0..63
    const int acol = (t & 3) * 8;      // halves
    const int srow = lane >> 2;        // 0..15
    const int scol = (lane & 3) * 8;

    for (int k0 = 0; k0 < K; k0 += 32) {
        {
            const float* xp = x + (size_t)(m0 + arow) * K + k0 + acol;
            float tmp[8];
            *reinterpret_cast<float4*>(tmp)     = *reinterpret_cast<const float4*>(xp);
            *reinterpret_cast<float4*>(tmp + 4) = *reinterpret_cast<const float4*>(xp + 4);
            half8_t h;
            #pragma unroll
            for (int j = 0; j < 8; ++j) h[j] = (_Float16)tmp[j];
            *reinterpret_cast<half8_t*>(As + arow * 32 + acol) = h;
        }
        gload_lds16(BT + (size_t)(n0 + wave * 16 + srow) * K + k0 + scol, Bs + wave * 512);
        gload_lds16(BT + (size_t)(n0 + 64 + wave * 16 + srow) * K + k0 + scol, Bs + 2048 + wave * 512);
        __syncthreads();
        half8_t af[2], bf[4];
        #pragma unroll
        for (int i = 0; i < 2; ++i)
            af[i] = *reinterpret_cast<const half8_t*>(As + (wr + i * 16 + l16) * 32 + quad * 8);
        #pragma unroll
        for (int j = 0; j < 4; ++j)
            bf[j] = *reinterpret_cast<const half8_t*>(Bs + (wc + j * 16 + l16) * 32 + quad * 8);
        #pragma unroll
        for (int i = 0; i < 2; ++i)
            #pragma unroll
            for (int j = 0; j < 4; ++j)
                acc[i][j] = __builtin_amdgcn_mfma_f32_16x16x32_f16(af[i], bf[j], acc[i][j], 0, 0, 0);
        __syncthreads();
    }

    const int bb = m0 >> 11;
    if (n0 < 256) {
        // Q: row-major, pre-scaled for exp2
        #pragma unroll
        for (int i = 0; i < 2; ++i)
            #pragma unroll
            for (int r = 0; r < 4; ++r) {
                int row = m0 + wr + i * 16 + quad * 4 + r;
                #pragma unroll
                for (int j = 0; j < 4; ++j)
                    qh[(size_t)row * 256 + n0 + wc + j * 16 + l16] =
                        (_Float16)(acc[i][j][r] * QSCALE);
            }
    } else if (n0 < 512) {
        // K: kpack[bh][tok][d]
        #pragma unroll
        for (int i = 0; i < 2; ++i)
            #pragma unroll
            for (int r = 0; r < 4; ++r) {
                int tok = (m0 & 2047) + wr + i * 16 + quad * 4 + r;
                #pragma unroll
                for (int j = 0; j < 4; ++j) {
                    int kc = n0 + wc + j * 16 + l16 - 256;
                    int hh = kc >> 5, dd = kc & 31;
                    kpack[((size_t)(bb * NHEADS + hh) * 2048 + tok) * 32 + dd] =
                        (_Float16)acc[i][j][r];
                }
            }
    } else {
        // V: vp[bh][chunk][d][tok%32], 4 tokens per half4 store
        #pragma unroll
        for (int i = 0; i < 2; ++i) {
            int tok0 = (m0 & 2047) + wr + i * 16 + quad * 4;
            int chunk = tok0 >> 5, tl = tok0 & 31;
            #pragma unroll
            for (int j = 0; j < 4; ++j) {
                int vc = n0 + wc + j * 16 + l16 - 512;
                int hh = vc >> 5, dd = vc & 31;
                half4_t p;
                #pragma unroll
                for (int r = 0; r < 4; ++r) p[r] = (_Float16)acc[i][j][r];
                *reinterpret_cast<half4_t*>(
                    vp + (((size_t)(bb * NHEADS + hh) * 64 + chunk) * 32 + dd) * 32 + tl) = p;
            }
        }
    }
}

// ---------------------------------------------------------------------------
// MFMA flash attention v10 = R8's v7 core + exp2(prescaled Q) + ones-MFMA
// denominator + per-head-contiguous NUM (block-private 16KB region -> no
// write amplification). 64 q/wave, kh x2, direct-global packed K/V reads,
// LDS only for the E round-trip. Grid: 512 = (b,h) x 8 qb(256) x 2 kh(1024).
// ---------------------------------------------------------------------------
__global__ __launch_bounds__(256, 2) void attn_v10(const _Float16* __restrict__ qh,
                                                   const _Float16* __restrict__ kpack,
                                                   const _Float16* __restrict__ vp,
                                                   _Float16* __restrict__ NUM,
                                                   float* __restrict__ DEN) {
    __shared__ alignas(16) _Float16 es[4][64][40];
    const int bid = blockIdx.x;
    const int kh = bid & 1;
    const int qb = (bid >> 1) & 7;
    const int bh = bid >> 4;
    const int b = bh >> 3, h = bh & 7;
    const int t = threadIdx.x, lane = t & 63, wave = t >> 6;
    const int l16 = lane & 15, quad = lane >> 4;
    const int bN = b * 2048;
    const int q0w = qb * 256 + wave * 64;
    const int kbeg = kh * 1024;

    // Q fragments (B-operand of S^T): 4 groups of 16 q (pre-scaled by QSCALE).
    half8_t qf[4];
    {
        const _Float16* qrow = qh + (size_t)(bN + q0w + l16) * 256 + h * HDIM + quad * 8;
        #pragma unroll
        for (int g = 0; g < 4; ++g)
            qf[g] = *reinterpret_cast<const half8_t*>(qrow + (size_t)g * 16 * 256);
    }

    const _Float16* kb_ = kpack + (size_t)bh * 65536;   // [2048][32]
    const _Float16* vb_ = vp + (size_t)bh * 65536;      // [64][32][32]

    float4_t num[4][2], dacc[4];
    #pragma unroll
    for (int g = 0; g < 4; ++g) {
        num[g][0] = (float4_t){0.f, 0.f, 0.f, 0.f};
        num[g][1] = (float4_t){0.f, 0.f, 0.f, 0.f};
        dacc[g]   = (float4_t){0.f, 0.f, 0.f, 0.f};
    }
    half8_t ones;
    #pragma unroll
    for (int j = 0; j < 8; ++j) ones[j] = (_Float16)1.0f;

    _Float16* esw = &es[wave][0][0];
    const float4_t z = {0.f, 0.f, 0.f, 0.f};

    for (int k0 = kbeg; k0 < kbeg + 1024; k0 += 64) {
        // K frags: 4 x 1KB contiguous; V frags: 2 chunks x 2 hd-halves x 1KB.
        half8_t kf[4], vf[4];
        #pragma unroll
        for (int j = 0; j < 4; ++j)
            kf[j] = *reinterpret_cast<const half8_t*>(
                kb_ + (size_t)(k0 + j * 16 + l16) * 32 + quad * 8);
        const int c0 = k0 >> 5;
        #pragma unroll
        for (int s = 0; s < 2; ++s)
            #pragma unroll
            for (int m = 0; m < 2; ++m)
                vf[s * 2 + m] = *reinterpret_cast<const half8_t*>(
                    vb_ + ((size_t)(c0 + s) * 32 + m * 16 + l16) * 32 + quad * 8);

        // S^T = K Q'^T : lane holds S^T[key=kb*16+quad*4+r][q=g*16+l16]
        float4_t st[4][4];
        #pragma unroll
        for (int kb = 0; kb < 4; ++kb)
            #pragma unroll
            for (int g = 0; g < 4; ++g)
                st[kb][g] = __builtin_amdgcn_mfma_f32_16x16x32_f16(kf[kb], qf[g], z, 0, 0, 0);

        // e = exp2(s') -> fp16 (bare v_exp_f32 + cvt)
        half4_t ep[4][4];
        #pragma unroll
        for (int kb = 0; kb < 4; ++kb)
            #pragma unroll
            for (int g = 0; g < 4; ++g)
                #pragma unroll
                for (int r = 0; r < 4; ++r)
                    ep[kb][g][r] = (_Float16)__builtin_exp2f(st[kb][g][r]);

        // Two 32-key chunks: E -> LDS (b64), A-frags back (b128), PV + denom.
        #pragma unroll
        for (int s = 0; s < 2; ++s) {
            #pragma unroll
            for (int tt = 0; tt < 2; ++tt)
                #pragma unroll
                for (int g = 0; g < 4; ++g)
                    *reinterpret_cast<half4_t*>(
                        esw + (g * 16 + l16) * 40 + tt * 16 + quad * 4) = ep[s * 2 + tt][g];

            #pragma unroll
            for (int g = 0; g < 4; ++g) {
                half8_t ef = *reinterpret_cast<const half8_t*>(
                    esw + (g * 16 + l16) * 40 + quad * 8);
                num[g][0] = __builtin_amdgcn_mfma_f32_16x16x32_f16(ef, vf[s * 2],     num[g][0], 0, 0, 0);
                num[g][1] = __builtin_amdgcn_mfma_f32_16x16x32_f16(ef, vf[s * 2 + 1], num[g][1], 0, 0, 0);
                dacc[g]   = __builtin_amdgcn_mfma_f32_16x16x32_f16(ef, ones,          dacc[g],   0, 0, 0);
            }
        }
    }

    // NUM: per-head-contiguous [kh][bh][tok][32] — block-private dense 16KB.
    _Float16* ob = NUM + (size_t)kh * 2097152 + ((size_t)bh * 2048 + q0w) * 32;
    #pragma unroll
    for (int g = 0; g < 4; ++g)
        #pragma unroll
        for (int r = 0; r < 4; ++r) {
            size_t ro = (size_t)(g * 16 + quad * 4 + r) * 32;
            ob[ro + l16]      = (_Float16)num[g][0][r];
            ob[ro + 16 + l16] = (_Float16)num[g][1][r];
        }
    // DEN partials (fp32): dacc cols all equal; lane l16==0 of each quad writes.
    if (l16 == 0) {
        #pragma unroll
        for (int g = 0; g < 4; ++g)
            #pragma unroll
            for (int r = 0; r < 4; ++r)
                DEN[kh * 65536 + bh * 2048 + q0w + g * 16 + quad * 4 + r] = dacc[g][r];
    }
}

// ---------------------------------------------------------------------------
// gemm2 + combine fused: out = [(N0+N1)*rcp(D0+D1+eps)] @ WoT^T + bout (fp32).
// 64x64 tile, BK=32, 4 waves (32x32). A synthesized from per-head-contiguous
// NUM partials (dense 4KB gathers); reciprocals hoisted. 512 blocks.
// ---------------------------------------------------------------------------
__global__ __launch_bounds__(256) void gemm2c(const _Float16* __restrict__ NUM,
                                              const float* __restrict__ DEN,
                                              const _Float16* __restrict__ BT,
                                              const float* __restrict__ bias,
                                              float* __restrict__ out) {
    __shared__ alignas(16) _Float16 As[64 * 32];
    __shared__ alignas(16) _Float16 Bs[64 * 32];
    const int t = threadIdx.x, lane = t & 63, wave = t >> 6;
    const int l16 = lane & 15, quad = lane >> 4;
    const int m0 = blockIdx.y * 64, n0 = blockIdx.x * 64;
    const int wr = (wave >> 1) * 32, wc = (wave & 1) * 32;
    const int bb = m0 >> 11;

    const int arow = t >> 2;            // 0..63
    const int acol = (t & 3) * 8;       // halves
    const int tok = (m0 + arow) & 2047;
    _Float16 rcp8[8];
    #pragma unroll
    for (int hh = 0; hh < 8; ++hh) {
        int di = (bb * 8 + hh) * 2048 + tok;
        rcp8[hh] = (_Float16)(1.f / (DEN[di] + DEN[di + 65536] + 1e-6f));
    }

    float4_t acc[2][2];
    #pragma unroll
    for (int i = 0; i < 2; ++i)
        #pragma unroll
        for (int j = 0; j < 2; ++j) acc[i][j] = (float4_t){0.f, 0.f, 0.f, 0.f};

    for (int k0 = 0; k0 < 256; k0 += 32) {
        const int hh = k0 >> 5;
        const _Float16* np = NUM + (((size_t)(bb * 8 + hh) * 2048 + tok) * 32) + acol;
        half8_t s0 = *reinterpret_cast<const half8_t*>(np);
        half8_t s1 = *reinterpret_cast<const half8_t*>(np + 2097152);
        *reinterpret_cast<half8_t*>(As + arow * 32 + acol) = (s0 + s1) * rcp8[hh];
        gload_lds16(BT + (size_t)(n0 + arow) * 256 + k0 + acol, Bs + t * 8);
        __syncthreads();
        half8_t af[2], bf[2];
        #pragma unroll
        for (int i = 0; i < 2; ++i)
            af[i] = *reinterpret_cast<const half8_t*>(As + (wr + i * 16 + l16) * 32 + quad * 8);
        #pragma unroll
        for (int j = 0; j < 2; ++j)
            bf[j] = *reinterpret_cast<const half8_t*>(Bs + (wc + j * 16 + l16) * 32 + quad * 8);
        #pragma unroll
        for (int i = 0; i < 2; ++i)
            #pragma unroll
            for (int j = 0; j < 2; ++j)
                acc[i][j] = __builtin_amdgcn_mfma_f32_16x16x32_f16(af[i], bf[j], acc[i][j], 0, 0, 0);
        __syncthreads();
    }

    #pragma unroll
    for (int i = 0; i < 2; ++i)
        #pragma unroll
        for (int r = 0; r < 4; ++r) {
            int row = m0 + wr + i * 16 + quad * 4 + r;
            #pragma unroll
            for (int j = 0; j < 2; ++j) {
                int col = n0 + wc + j * 16 + l16;
                out[(size_t)row * 256 + col] = acc[i][j][r] + bias[col];
            }
        }
}

extern "C" void kernel_launch(void* const* d_in, const int* in_sizes, int n_in,
                              void* d_out, int out_size, void* d_ws, size_t ws_size,
                              hipStream_t stream) {
    const float* x    = (const float*)d_in[0];
    const float* Wqkv = (const float*)d_in[1];
    const float* Wout = (const float*)d_in[2];
    const float* bout = (const float*)d_in[3];
    float* out = (float*)d_out;
    const int M = 8192;

    _Float16* WqT   = (_Float16*)d_ws;                 // [768,256]
    _Float16* WoT   = WqT + 768 * 256;                 // [256,256]
    _Float16* qh    = WoT + 256 * 256;                 // [8192,256] (pre-scaled)
    _Float16* kpack = qh + (size_t)M * DIM;            // [32][2048][32]
    _Float16* vp    = kpack + (size_t)32 * 2048 * 32;  // [32][64][32][32]
    _Float16* NUM   = vp + (size_t)32 * 2048 * 32;     // [2][32][2048][32]
    float*    DEN   = (float*)(NUM + (size_t)2 * M * DIM);  // [2][65536]

    hipLaunchKernelGGL(prep_w, dim3(256), dim3(256), 0, stream, Wqkv, Wout, WqT, WoT);
    hipLaunchKernelGGL(gemm_qkv, dim3(6, 128), dim3(256), 0, stream, x, WqT, qh, kpack, vp);
    hipLaunchKernelGGL(attn_v10, dim3(512), dim3(256), 0, stream, qh, kpack, vp, NUM, DEN);
    hipLaunchKernelGGL(gemm2c, dim3(4, 128), dim3(256), 0, stream, NUM, DEN, WoT, bout, out);
}